// Round 5
// baseline (276.295 us; speedup 1.0000x reference)
//
#include <hip/hip_runtime.h>
#include <hip/hip_bf16.h>
#include <stdint.h>

// ============================================================================
// Attention: out = softmax(mask((X_q Wq + bq)(X_k Wk + bk)^T / 8)) (X_v Wv + bv)
// B=4 S=4096 H=1024 D=64, fp32 in/out.
//
// Pipeline:
//   setup : W^T -> bf16 (plain [n][1024]), mask -> float bias {0, -1e30}
//   proj  : [R9] 1536 x 2-wave blocks, 32-row strip. FULL-STRIP staging:
//           each wave reads its 16 rows CONTIGUOUSLY (4KB/row sequential,
//           depth-2 row pipeline, named regs), converts fp32->bf16 in the
//           staging phase, writes swizzled bf16 [32][1024] LDS image (64KB).
//           ONE __syncthreads, then a BARRIER-FREE K-loop: 64 x
//           {ds_read_b128 A-frag + MFMA}, W prefetched 1-deep (R8's clean
//           named-reg pattern). Rationale: R4/R5/R8 (3 different staging
//           structures) all plateau at 83us / 1.3 TB/s; they share (1) 256B
//           -per-row chunked reads (DRAM-granularity-hostile) and (2) a
//           full-drain barrier round trip every chunk (16 lockstep latency
//           round trips, 5.2us each measured). R7's spill traffic proved
//           the memory system delivers 2.6+ TB/s for big unsynchronized
//           bursts. R9 makes X reads fully sequential and removes all
//           K-loop barriers. Swizzle phys=(c16&~7)|((c16^(r&7)^((c16>>3)
//           &7))&7) is bank-optimal for both row-writes and column-reads.
//   flash : S^T = K*Q^T per 32x32 tile, p = exp2(s*0.125*log2e + bias),
//           PV via shfl_xor(32) lane-pair exchange (C-layout -> B-operand),
//           one-pass softmax (logits bounded, no running max needed),
//           4-way key-split per block, pairwise LDS combine.
//           (flash keeps DMA staging: its tiles are L2-resident -> fast.)
//
// q/k/vT global tiles keep the chunk-XOR swizzle (c ^ (row&7)) because flash
// stages them into LDS verbatim via global_load_lds and ds_read_b128's them.
// ============================================================================

typedef __bf16 bf16;
typedef __bf16 bf16x8 __attribute__((ext_vector_type(8)));
typedef float f32x16 __attribute__((ext_vector_type(16)));

union B8 { uint4 u; bf16x8 v; uint32_t w[4]; };

#define AS1 __attribute__((address_space(1)))
#define AS3 __attribute__((address_space(3)))

__device__ __forceinline__ void async16(const void* g, void* l) {
  // global -> LDS DMA, 16B per lane; LDS dest = wave-uniform base + lane*16
  __builtin_amdgcn_global_load_lds((AS1 void*)(g), (AS3 void*)(l), 16, 0, 0);
}

#define KSC 0.18033688011112042f  // 0.125 * log2(e)

// ---------------------------------------------------------------------------
// setup: items 0..24575   : W transpose+cast, one 16B wT chunk per thread
//        items 24576..28671: mask -> bias, 4 elements per thread (float4)
// wT layout: [mat][n][1024 k] bf16, plain row-major (read from global by proj)
// ---------------------------------------------------------------------------
__global__ void setup_kernel(const float* __restrict__ Wq, const float* __restrict__ Wk,
                             const float* __restrict__ Wv, const int* __restrict__ mask,
                             bf16* __restrict__ wT, float* __restrict__ biasArr)
{
  int item = blockIdx.x * 256 + threadIdx.x;
  if (item < 24576) {
    int mat = item >> 13;          // 8192 items per matrix
    int rem = item & 8191;
    int n   = rem >> 7;            // 0..63 (col of W)
    int c   = rem & 127;           // 16B chunk id along k
    const float* W = (mat == 0) ? Wq : (mat == 1) ? Wk : Wv;
    union { bf16 b[8]; uint4 u; } pk;
    #pragma unroll
    for (int j = 0; j < 8; ++j)
      pk.b[j] = (bf16)W[(c * 8 + j) * 64 + n];
    bf16* o = wT + mat * 65536;
    *(uint4*)(o + n * 1024 + c * 8) = pk.u;
  } else {
    int i = (item - 24576) << 2;
    const int4 m = *(const int4*)(mask + i);
    float4 b;
    b.x = m.x ? 0.0f : -1e30f;
    b.y = m.y ? 0.0f : -1e30f;
    b.z = m.z ? 0.0f : -1e30f;
    b.w = m.w ? 0.0f : -1e30f;
    *(float4*)(biasArr + i) = b;
  }
}

// ---------------------------------------------------------------------------
// proj: 1536 blocks x 128 threads (2 waves). Strip = 32 rows of one matrix.
// Wave w: stages rows [16w,16w+16) contiguously; computes cols [32w,32w+32).
// LDS: 64KB bf16 [32 r][1024 k], 16B chunk c16 of row r at slot
//      PHYS(c16,r) = (c16&~7) | ((c16 ^ (r&7) ^ ((c16>>3)&7)) & 7).
// ---------------------------------------------------------------------------
__global__ __launch_bounds__(128) void proj_kernel(
    const float* __restrict__ Xq, const float* __restrict__ Xk, const float* __restrict__ Xv,
    const bf16* __restrict__ wT,
    const float* __restrict__ bq, const float* __restrict__ bk, const float* __restrict__ bv,
    bf16* __restrict__ qo, bf16* __restrict__ ko, bf16* __restrict__ vTo)
{
  const int bx = blockIdx.x;
  const int mat = bx >> 9;            // 512 strips per matrix
  const int m0 = (bx & 511) << 5;     // strip base row
  const float* X    = (mat == 0) ? Xq : (mat == 1) ? Xk : Xv;
  const float* bias = (mat == 0) ? bq : (mat == 1) ? bk : bv;
  const bf16* w = wT + mat * 65536;

  __shared__ __align__(16) char psm[65536];   // bf16 X strip; cs overlays after
  bf16* cs = (bf16*)psm;                      // 4 KB C bounce tile (post K-loop)

  const int tid  = threadIdx.x;
  const int wv   = tid >> 6;      // wave id = row-half (stage) = col-half (compute)
  const int lane = tid & 63;
  const int half = lane >> 5;
  const int ln   = lane & 31;

  const bf16* w0 = w + ((wv << 5) + ln) * 1024 + half * 8;
  float b0v = bias[(wv << 5) + ln];

  // ---------------- staging: 16 contiguous rows per wave, depth-2 ----------
  // lane covers floats [lane*16, lane*16+16) of each row -> bf16 chunks
  // c16a = 2*lane, c16b = 2*lane+1.
  const float* xrow = X + (size_t)(m0 + (wv << 4)) * 1024 + lane * 16;
  const int c16a = lane * 2;
  const int c16b = lane * 2 + 1;
  const int gx   = (lane >> 2) & 7;           // (c16>>3)&7, same for a and b

  float4 a0, a1, a2, a3, b0, b1, b2, b3;      // named depth-2 row regs

  #define LDROW(s0, s1, s2, s3, rr)                                        \
    { const float* p_ = xrow + (size_t)(rr) * 1024;                        \
      s0 = *(const float4*)(p_);      s1 = *(const float4*)(p_ + 4);       \
      s2 = *(const float4*)(p_ + 8);  s3 = *(const float4*)(p_ + 12); }

  #define WRROW(s0, s1, s2, s3, rr)                                        \
    { int r_ = (wv << 4) + (rr);                                           \
      int pa_ = (c16a & ~7) | ((c16a ^ (r_ & 7) ^ gx) & 7);                \
      int pb_ = (c16b & ~7) | ((c16b ^ (r_ & 7) ^ gx) & 7);                \
      union { bf16 b[8]; uint4 q; } ua_, ub_;                              \
      ua_.b[0] = (bf16)s0.x; ua_.b[1] = (bf16)s0.y;                        \
      ua_.b[2] = (bf16)s0.z; ua_.b[3] = (bf16)s0.w;                        \
      ua_.b[4] = (bf16)s1.x; ua_.b[5] = (bf16)s1.y;                        \
      ua_.b[6] = (bf16)s1.z; ua_.b[7] = (bf16)s1.w;                        \
      ub_.b[0] = (bf16)s2.x; ub_.b[1] = (bf16)s2.y;                        \
      ub_.b[2] = (bf16)s2.z; ub_.b[3] = (bf16)s2.w;                        \
      ub_.b[4] = (bf16)s3.x; ub_.b[5] = (bf16)s3.y;                        \
      ub_.b[6] = (bf16)s3.z; ub_.b[7] = (bf16)s3.w;                        \
      *(uint4*)(psm + r_ * 2048 + pa_ * 16) = ua_.q;                       \
      *(uint4*)(psm + r_ * 2048 + pb_ * 16) = ub_.q; }

  LDROW(a0, a1, a2, a3, 0)
  for (int rr = 0; rr < 16; rr += 2) {
    LDROW(b0, b1, b2, b3, rr + 1)
    WRROW(a0, a1, a2, a3, rr)                 // waits a*'s vmcnt only
    if (rr < 14) LDROW(a0, a1, a2, a3, rr + 2)
    WRROW(b0, b1, b2, b3, rr + 1)
  }
  #undef LDROW
  #undef WRROW

  __syncthreads();   // strip staged by both waves (drains everything, once)

  // ---------------- K-loop: barrier-free, W prefetched 1-deep --------------
  uint4 cw0, cw1, cw2, cw3, sw0, sw1, sw2, sw3;
  #define LW1(dst, s_, j)  { dst = *(const uint4*)(w0 + (j) * 64 + (s_) * 16); }
  #define LOADW_C(j) LW1(cw0, 0, j) LW1(cw1, 1, j) LW1(cw2, 2, j) LW1(cw3, 3, j)
  #define LOADW_S(j) LW1(sw0, 0, j) LW1(sw1, 1, j) LW1(sw2, 2, j) LW1(sw3, 3, j)

  // A-fragment: row ln, k-window [c*64+s*16+half*8, +8) -> chunk c16 = c*8+s*2+half
  #define CSTN(c_, s_, WREG)                                               \
    { int c16_ = (c_) * 8 + (s_) * 2 + half;                               \
      int phys_ = (c16_ & ~7) | ((c16_ ^ (ln & 7) ^ ((c_) & 7)) & 7);      \
      B8 af_; af_.u = *(const uint4*)(psm + ln * 2048 + phys_ * 16);       \
      B8 wa_; wa_.u = WREG;                                                \
      acc = __builtin_amdgcn_mfma_f32_32x32x16_bf16(af_.v, wa_.v, acc, 0, 0, 0); }

  f32x16 acc = {};   // 32 rows x cols [32wv, 32wv+32)

  LOADW_C(0);
  for (int c = 0; c < 16; ++c) {
    if (c < 15) { LOADW_S(c + 1) }
    CSTN(c, 0, cw0) CSTN(c, 1, cw1) CSTN(c, 2, cw2) CSTN(c, 3, cw3)
    if (c < 15) { cw0 = sw0; cw1 = sw1; cw2 = sw2; cw3 = sw3; }
  }

  #undef LW1
  #undef LOADW_C
  #undef LOADW_S
  #undef CSTN

  __syncthreads();   // all waves done reading the X strip; cs may overlay

  // epilogue: bias add, write un-swizzled [32 m][64 n] bf16 tile to LDS
  #pragma unroll
  for (int r = 0; r < 16; ++r) {
    int mrow = (r & 3) + 8 * (r >> 2) + 4 * half;   // C row map (m74/m101)
    cs[mrow * 64 + (wv << 5) + ln] = (bf16)(acc[r] + b0v);
  }
  __syncthreads();

  if (mat < 2) {
    // q/k: row-major [16384][64] bf16, chunk c of row s at slot c^(s&7)
    bf16* gout = (mat == 0) ? qo : ko;
    #pragma unroll
    for (int p = 0; p < 2; ++p) {
      int id = p * 128 + tid;     // 0..255
      int r = id >> 3;            // 0..31
      int c = id & 7;
      int phys = c ^ (r & 7);     // m0 % 32 == 0 so (m0+r)&7 == r&7
      *(uint4*)(gout + (size_t)(m0 + r) * 64 + phys * 8) = *(const uint4*)(cs + r * 64 + c * 8);
    }
  } else {
    // v: transposed [b][64 d][4096 s] bf16, chunk swizzle per 64-key tile
    int batch = m0 >> 12;
    int sk = m0 & 4095;           // key offset within batch
    int tb = sk & ~63;            // 64-key tile base
    int halfTile = (sk >> 5) & 1; // which half of the tile this strip covers
    #pragma unroll
    for (int p = 0; p < 2; ++p) {
      int id = p * 128 + tid;     // 0..255
      int d = id >> 2;            // 0..63
      int j = id & 3;             // chunk within strip
      union { bf16 b[8]; uint4 u; } pk;
      #pragma unroll
      for (int t = 0; t < 8; ++t) pk.b[t] = cs[(j * 8 + t) * 64 + d];
      int cl = halfTile * 4 + j;  // logical chunk in 64-key tile
      int phys = cl ^ (d & 7);
      *(uint4*)(vTo + ((size_t)batch * 64 + d) * 4096 + tb + phys * 8) = pk.u;
    }
  }
}

// ---------------------------------------------------------------------------
// flash: block = 64 queries (one batch), 4 waves, wave w owns keys
//        [w*1024, w*1024+1024) in 16 tiles of 64; wave-private LDS streams.
// ---------------------------------------------------------------------------
__global__ __launch_bounds__(256, 2) void flash_kernel(
    const bf16* __restrict__ qb, const bf16* __restrict__ kb, const bf16* __restrict__ vT,
    const float* __restrict__ biasArr, float* __restrict__ out)
{
  __shared__ __align__(16) char smem[65536];
  bf16* ksb = (bf16*)smem;            // [4][64*64] K tiles
  bf16* vsb = (bf16*)(smem + 32768);  // [4][64*64] V^T tiles

  const int tid = threadIdx.x;
  const int lane = tid & 63;
  const int wv = tid >> 6;
  const int half = lane >> 5;
  const int ln = lane & 31;

  const int batch = blockIdx.x >> 6;
  const int q0 = (blockIdx.x & 63) << 6;

  // Q fragments for both 32-query blocks (stay in registers)
  bf16x8 qf[2][4];
  const bf16* qbase = qb + ((size_t)batch * 4096 + q0) * 64;
  #pragma unroll
  for (int qk = 0; qk < 2; ++qk)
  #pragma unroll
  for (int s = 0; s < 4; ++s) {
    int qq = (qk << 5) + ln;
    int phys = (2 * s + half) ^ (qq & 7);
    B8 t; t.u = *(const uint4*)(qbase + qq * 64 + phys * 8);
    qf[qk][s] = t.v;
  }

  f32x16 acc[2][2] = {{{}, {}}, {{}, {}}};   // [qblk][d-half], C: col=q, rows=d
  float den0 = 0.f, den1 = 0.f;

  bf16* kds = ksb + wv * 4096;
  bf16* vds = vsb + wv * 4096;
  const bf16* kgb = kb + (size_t)batch * 4096 * 64;
  const bf16* vgb = vT + (size_t)batch * 64 * 4096;
  const float* barr = biasArr + batch * 4096;

  for (int it = 0; it < 16; ++it) {
    const int key0 = wv * 1024 + it * 64;
    __syncthreads();  // drain previous tile's ds_reads before DMA overwrites
    // stage K tile [64 keys][64 d] (8KB contiguous in global)
    const bf16* ksrc = kgb + (size_t)key0 * 64;
    #pragma unroll
    for (int i = 0; i < 8; ++i)
      async16((const char*)ksrc + i * 1024 + lane * 16, (char*)kds + i * 1024);
    // stage V^T tile [64 d][64 keys] (128B per d-row, stride 8KB)
    const bf16* vsrc = vgb + key0;
    #pragma unroll
    for (int i = 0; i < 8; ++i)
      async16((const char*)vsrc + ((size_t)(i * 8 + (lane >> 3)) * 4096 + (lane & 7) * 8) * 2,
              (char*)vds + i * 1024);
    __syncthreads();  // DMA complete

    #pragma unroll
    for (int st = 0; st < 2; ++st) {
      // S^T tile = K * Q^T : rows = 32 keys, cols = 32 queries
      f32x16 s0 = {};
      f32x16 s1 = {};
      #pragma unroll
      for (int s = 0; s < 4; ++s) {
        int key = (st << 5) + ln;
        B8 af; af.u = *(const uint4*)(kds + key * 64 + (((2 * s + half) ^ (key & 7)) << 3));
        s0 = __builtin_amdgcn_mfma_f32_32x32x16_bf16(af.v, qf[0][s], s0, 0, 0, 0);
        s1 = __builtin_amdgcn_mfma_f32_32x32x16_bf16(af.v, qf[1][s], s1, 0, 0, 0);
      }
      // bias per C-row (key): reg r -> key (r&3)+8*(r>>2)+4*half (tile-local)
      float bb[16];
      #pragma unroll
      for (int g = 0; g < 4; ++g)
        *(float4*)&bb[4 * g] = *(const float4*)(barr + key0 + (st << 5) + 8 * g + (half << 2));
      // p = exp2(s*KSC + bias); accumulate denominator; pack bf16 pairs
      uint32_t pk0[8], pk1[8];
      #pragma unroll
      for (int i = 0; i < 8; ++i) {
        float a0 = __builtin_amdgcn_exp2f(fmaf(s0[2 * i],     KSC, bb[2 * i]));
        float a1 = __builtin_amdgcn_exp2f(fmaf(s0[2 * i + 1], KSC, bb[2 * i + 1]));
        float c0 = __builtin_amdgcn_exp2f(fmaf(s1[2 * i],     KSC, bb[2 * i]));
        float c1 = __builtin_amdgcn_exp2f(fmaf(s1[2 * i + 1], KSC, bb[2 * i + 1]));
        den0 += a0 + a1;
        den1 += c0 + c1;
        union { bf16 b[2]; uint32_t u; } u0, u1;
        u0.b[0] = (bf16)a0; u0.b[1] = (bf16)a1;
        u1.b[0] = (bf16)c0; u1.b[1] = (bf16)c1;
        pk0[i] = u0.u; pk1[i] = u1.u;
      }
      // lane-pair exchange: C-layout P^T -> B-operand fragments
      uint32_t xp0[8], xp1[8];
      #pragma unroll
      for (int i = 0; i < 8; ++i) {
        xp0[i] = (uint32_t)__shfl_xor((int)pk0[i], 32);
        xp1[i] = (uint32_t)__shfl_xor((int)pk1[i], 32);
      }
      #pragma unroll
      for (int t = 0; t < 2; ++t) {
        B8 p0f, p1f;
        p0f.w[0] = half ? xp0[4 * t + 2] : pk0[4 * t];
        p0f.w[1] = half ? xp0[4 * t + 3] : pk0[4 * t + 1];
        p0f.w[2] = half ? pk0[4 * t + 2] : xp0[4 * t];
        p0f.w[3] = half ? pk0[4 * t + 3] : xp0[4 * t + 1];
        p1f.w[0] = half ? xp1[4 * t + 2] : pk1[4 * t];
        p1f.w[1] = half ? xp1[4 * t + 3] : pk1[4 * t + 1];
        p1f.w[2] = half ? pk1[4 * t + 2] : xp1[4 * t];
        p1f.w[3] = half ? pk1[4 * t + 3] : xp1[4 * t + 1];
        #pragma unroll
        for (int dh = 0; dh < 2; ++dh) {
          int d = (dh << 5) + ln;
          B8 vf; vf.u = *(const uint4*)(vds + d * 64 +
                          ((((st << 2) + (t << 1) + half) ^ (d & 7)) << 3));
          acc[0][dh] = __builtin_amdgcn_mfma_f32_32x32x16_bf16(vf.v, p0f.v, acc[0][dh], 0, 0, 0);
          acc[1][dh] = __builtin_amdgcn_mfma_f32_32x32x16_bf16(vf.v, p1f.v, acc[1][dh], 0, 0, 0);
        }
      }
    }
  }

  // full denominator per query (each half-lane saw half the keys)
  den0 += __shfl_xor(den0, 32);
  den1 += __shfl_xor(den1, 32);

  // pairwise combine of the 4 key-split partials through LDS (<= 35KB overlay)
  float* nb = (float*)smem;              // [2][64*68]
  float* dn = (float*)(smem + 34816);    // [2][64]

  __syncthreads();
  if (wv >= 2) {
    float* mynb = nb + (wv - 2) * 4352;
    #pragma unroll
    for (int qk = 0; qk < 2; ++qk)
    #pragma unroll
    for (int dh = 0; dh < 2; ++dh)
    #pragma unroll
    for (int g = 0; g < 4; ++g) {
      int q = (qk << 5) + ln;
      int d = 8 * g + (half << 2) + (dh << 5);
      f32x16 a = acc[qk][dh];
      *(float4*)(mynb + q * 68 + d) = make_float4(a[4*g], a[4*g+1], a[4*g+2], a[4*g+3]);
    }
    if (half == 0) {
      dn[(wv - 2) * 64 + ln]      = den0;
      dn[(wv - 2) * 64 + 32 + ln] = den1;
    }
  }
  __syncthreads();
  if (wv < 2) {
    float* pb = nb + wv * 4352;
    #pragma unroll
    for (int qk = 0; qk < 2; ++qk)
    #pragma unroll
    for (int dh = 0; dh < 2; ++dh)
    #pragma unroll
    for (int g = 0; g < 4; ++g) {
      int q = (qk << 5) + ln;
      int d = 8 * g + (half << 2) + (dh << 5);
      float4 t = *(const float4*)(pb + q * 68 + d);
      acc[qk][dh][4*g+0] += t.x; acc[qk][dh][4*g+1] += t.y;
      acc[qk][dh][4*g+2] += t.z; acc[qk][dh][4*g+3] += t.w;
    }
    den0 += dn[wv * 64 + ln];
    den1 += dn[wv * 64 + 32 + ln];
  }
  __syncthreads();
  if (wv < 2) {
    float* mynb = nb + wv * 4352;
    #pragma unroll
    for (int qk = 0; qk < 2; ++qk)
    #pragma unroll
    for (int dh = 0; dh < 2; ++dh)
    #pragma unroll
    for (int g = 0; g < 4; ++g) {
      int q = (qk << 5) + ln;
      int d = 8 * g + (half << 2) + (dh << 5);
      f32x16 a = acc[qk][dh];
      *(float4*)(mynb + q * 68 + d) = make_float4(a[4*g], a[4*g+1], a[4*g+2], a[4*g+3]);
    }
    if (half == 0) {
      dn[wv * 64 + ln]      = den0;
      dn[wv * 64 + 32 + ln] = den1;
    }
  }
  __syncthreads();
  // final: out[q][d] = (nb0+nb1)/(dn0+dn1), coalesced float4 stores
  #pragma unroll
  for (int p = 0; p < 4; ++p) {
    int i = p * 256 + tid;
    int qq = i >> 4;
    int d4 = (i & 15) << 2;
    float4 A = *(const float4*)(nb + qq * 68 + d4);
    float4 Bv = *(const float4*)(nb + 4352 + qq * 68 + d4);
    float dd = dn[qq] + dn[64 + qq];
    float inv = 1.0f / dd;
    float4 o = make_float4((A.x + Bv.x) * inv, (A.y + Bv.y) * inv,
                           (A.z + Bv.z) * inv, (A.w + Bv.w) * inv);
    *(float4*)(out + ((size_t)batch * 4096 + q0 + qq) * 64 + d4) = o;
  }
}

// ---------------------------------------------------------------------------
extern "C" void kernel_launch(void* const* d_in, const int* in_sizes, int n_in,
                              void* d_out, int out_size, void* d_ws, size_t ws_size,
                              hipStream_t stream)
{
  const float* query = (const float*)d_in[0];
  const float* key   = (const float*)d_in[1];
  const float* value = (const float*)d_in[2];
  const int*   mask  = (const int*)d_in[3];
  const float* Wq    = (const float*)d_in[4];
  const float* bq    = (const float*)d_in[5];
  const float* Wk    = (const float*)d_in[6];
  const float* bk    = (const float*)d_in[7];
  const float* Wv    = (const float*)d_in[8];
  const float* bv    = (const float*)d_in[9];
  float* out = (float*)d_out;

  // workspace carve (bf16 elems): q 1M, k 1M, vT 1M, wT 192K, bias 16K floats
  bf16* qb = (bf16*)d_ws;
  bf16* kb = qb + 1048576;
  bf16* vT = kb + 1048576;
  bf16* wT = vT + 1048576;                       // 3*64*1024
  float* biasArr = (float*)((char*)d_ws + 3 * 2097152 + 393216);

  setup_kernel<<<112, 256, 0, stream>>>(Wq, Wk, Wv, mask, wT, biasArr);
  proj_kernel<<<1536, 128, 0, stream>>>(query, key, value, wT, bq, bk, bv, qb, kb, vT);
  flash_kernel<<<256, 256, 0, stream>>>(qb, kb, vT, biasArr, out);
}

// Round 6
// 259.648 us; speedup vs baseline: 1.0641x; 1.0641x over previous
//
#include <hip/hip_runtime.h>
#include <hip/hip_bf16.h>
#include <stdint.h>

// ============================================================================
// Attention: out = softmax(mask((X_q Wq + bq)(X_k Wk + bk)^T / 8)) (X_v Wv + bv)
// B=4 S=4096 H=1024 D=64, fp32 in/out.
//
// Pipeline:
//   setup : W^T -> bf16 (plain [n][1024]), mask -> float bias {0, -1e30}
//   proj  : [R10] 768 x 4-wave blocks, 64-row strip, 2x2 wave grid:
//           wave (wr,wc) computes rows [32wr,+32) x cols [32wc,+32).
//           Evidence: R9's L3-resident dispatches (FETCH~0) ran the SAME
//           97us as HBM-fetching ones -> bottleneck is per-CU DELIVERED
//           bytes (~4.6 TB/s chip-wide incl. W re-reads), not HBM/L3/
//           granularity. R8 delivered X 192MB + W re-reads 192MB
//           (1536 blocks x 128KB, all L2-hit, invisible in FETCH).
//           R10 halves W traffic (768 blocks x 128KB = 96MB) by making
//           strips 2x taller, and bounces W through LDS so the two
//           row-waves share one read. X staged as bf16 (converted at
//           stage time; same single rounding -> identical numerics).
//           Schedule/barriers/scalar-named regs verbatim from R8 (the
//           no-spill config): per chunk {issue X+W global->regs, MFMA
//           from LDS, ds_write next chunk, lgkmcnt(0) + raw s_barrier}.
//           LDS 40KB -> 3 blocks/CU x 4 waves = 12 waves/CU (R8-equal).
//   flash : S^T = K*Q^T per 32x32 tile, p = exp2(s*0.125*log2e + bias),
//           PV via shfl_xor(32) lane-pair exchange (C-layout -> B-operand),
//           one-pass softmax (logits bounded, no running max needed),
//           4-way key-split per block, pairwise LDS combine.
//
// q/k/vT global tiles keep the chunk-XOR swizzle (c ^ (row&7)) because flash
// stages them into LDS verbatim via global_load_lds and ds_read_b128's them.
// ============================================================================

typedef __bf16 bf16;
typedef __bf16 bf16x8 __attribute__((ext_vector_type(8)));
typedef float f32x16 __attribute__((ext_vector_type(16)));

union B8 { uint4 u; bf16x8 v; uint32_t w[4]; };

#define AS1 __attribute__((address_space(1)))
#define AS3 __attribute__((address_space(3)))

__device__ __forceinline__ void async16(const void* g, void* l) {
  // global -> LDS DMA, 16B per lane; LDS dest = wave-uniform base + lane*16
  __builtin_amdgcn_global_load_lds((AS1 void*)(g), (AS3 void*)(l), 16, 0, 0);
}

#define KSC 0.18033688011112042f  // 0.125 * log2(e)

// ---------------------------------------------------------------------------
// setup: items 0..24575   : W transpose+cast, one 16B wT chunk per thread
//        items 24576..28671: mask -> bias, 4 elements per thread (float4)
// wT layout: [mat][n][1024 k] bf16, plain row-major (read from global by proj)
// ---------------------------------------------------------------------------
__global__ void setup_kernel(const float* __restrict__ Wq, const float* __restrict__ Wk,
                             const float* __restrict__ Wv, const int* __restrict__ mask,
                             bf16* __restrict__ wT, float* __restrict__ biasArr)
{
  int item = blockIdx.x * 256 + threadIdx.x;
  if (item < 24576) {
    int mat = item >> 13;          // 8192 items per matrix
    int rem = item & 8191;
    int n   = rem >> 7;            // 0..63 (col of W)
    int c   = rem & 127;           // 16B chunk id along k
    const float* W = (mat == 0) ? Wq : (mat == 1) ? Wk : Wv;
    union { bf16 b[8]; uint4 u; } pk;
    #pragma unroll
    for (int j = 0; j < 8; ++j)
      pk.b[j] = (bf16)W[(c * 8 + j) * 64 + n];
    bf16* o = wT + mat * 65536;
    *(uint4*)(o + n * 1024 + c * 8) = pk.u;
  } else {
    int i = (item - 24576) << 2;
    const int4 m = *(const int4*)(mask + i);
    float4 b;
    b.x = m.x ? 0.0f : -1e30f;
    b.y = m.y ? 0.0f : -1e30f;
    b.z = m.z ? 0.0f : -1e30f;
    b.w = m.w ? 0.0f : -1e30f;
    *(float4*)(biasArr + i) = b;
  }
}

// ---------------------------------------------------------------------------
// proj: 768 blocks x 256 threads (4 waves, 2x2 grid). Strip = 64 rows.
// LDS per K-chunk c: X [64 r][64 k] bf16 (8KB, dbuf) + W [64 n][64 k] bf16
// (8KB, dbuf) + cs [64][64] bf16 (8KB) = 40KB.
// 8-bf16 group g of row r lives at phys slot g ^ (r&7) (16B-granular XOR).
// ---------------------------------------------------------------------------
__global__ __launch_bounds__(256) void proj_kernel(
    const float* __restrict__ Xq, const float* __restrict__ Xk, const float* __restrict__ Xv,
    const bf16* __restrict__ wT,
    const float* __restrict__ bq, const float* __restrict__ bk, const float* __restrict__ bv,
    bf16* __restrict__ qo, bf16* __restrict__ ko, bf16* __restrict__ vTo)
{
  const int bx = blockIdx.x;
  const int mat = bx >> 8;            // 256 strips per matrix
  const int m0 = (bx & 255) << 6;     // strip base row (64-aligned)
  const float* X    = (mat == 0) ? Xq : (mat == 1) ? Xk : Xv;
  const float* bias = (mat == 0) ? bq : (mat == 1) ? bk : bv;
  const bf16* wm = wT + mat * 65536;

  __shared__ __align__(16) char xsm[2][8192];   // X chunk dbuf (bf16 [64][64])
  __shared__ __align__(16) char wsm[2][8192];   // W chunk dbuf (bf16 [64][64])
  __shared__ __align__(16) bf16 cs[64 * 64];    // C bounce tile

  const int tid  = threadIdx.x;
  const int wv   = tid >> 6;
  const int lane = tid & 63;
  const int half = lane >> 5;
  const int ln   = lane & 31;
  const int wr   = wv >> 1;       // row-half of output
  const int wc   = wv & 1;        // col-half of output

  // X stage mapping: wave stages rows [16wv,16wv+16); lane -> (row, 8B slot)
  const int drow = lane >> 4;             // row within 4-row group
  const int dcl  = lane & 15;             // logical 8B-bf16 slot (4 floats)
  const int r0   = (wv << 4) + drow;      // rows r0, r0+4, r0+8, r0+12
  const float* xp = X + (size_t)(m0 + r0) * 1024 + dcl * 4;

  // W stage mapping: wave stages n-rows [16wv,+16) in 2 rounds of 8
  const int wn0 = (wv << 4) + (lane >> 3);
  const int wj  = lane & 7;               // logical 16B chunk within n-row
  const bf16* wp0 = wm + (size_t)wn0 * 1024 + wj * 8;

  // compute mapping
  const int ar  = (wr << 5) + ln;         // A-operand row (X row)
  const int an  = (wc << 5) + ln;         // B-operand col (W col)
  const int ar7 = ar & 7;
  const int an7 = an & 7;

  float b0v = bias[an];

  // all-scalar staging state (no VGPR arrays -- R6/R7 spill lesson)
  float4 sx0, sx1, sx2, sx3;
  uint4  sw0, sw1;

  #define LOADX(j) { const float* p_ = xp + (j) * 64;                       \
      sx0 = *(const float4*)(p_);                                           \
      sx1 = *(const float4*)(p_ + 4096);                                    \
      sx2 = *(const float4*)(p_ + 8192);                                    \
      sx3 = *(const float4*)(p_ + 12288); }

  #define LOADW(j) { const bf16* q_ = wp0 + (j) * 64;                       \
      sw0 = *(const uint4*)(q_);                                            \
      sw1 = *(const uint4*)(q_ + 8192); }

  #define WX1(s_, i_) { int rl_ = r0 + (i_) * 4;                            \
      int byte_ = rl_ * 128 + (((dcl >> 1) ^ (rl_ & 7)) << 4) + ((dcl & 1) << 3); \
      union { bf16 b[4]; uint2 u; } pk_;                                    \
      pk_.b[0] = (bf16)(s_).x; pk_.b[1] = (bf16)(s_).y;                     \
      pk_.b[2] = (bf16)(s_).z; pk_.b[3] = (bf16)(s_).w;                     \
      *(uint2*)(dst_ + byte_) = pk_.u; }

  #define WRITEX(bufp) { char* dst_ = (bufp);                               \
      WX1(sx0, 0) WX1(sx1, 1) WX1(sx2, 2) WX1(sx3, 3) }

  #define WRITEW(bufp) { char* dw_ = (bufp);                                \
      *(uint4*)(dw_ + wn0 * 128 + ((wj ^ (wn0 & 7)) << 4)) = sw0;           \
      int n1_ = wn0 + 8;                                                    \
      *(uint4*)(dw_ + n1_ * 128 + ((wj ^ (n1_ & 7)) << 4)) = sw1; }

  #define COMPUTE(xbp, wbp) { const char* xq_ = (xbp); const char* wq_ = (wbp); \
      _Pragma("unroll")                                                     \
      for (int s_ = 0; s_ < 4; ++s_) {                                      \
        int c16_ = 2 * s_ + half;                                           \
        B8 af_; af_.u = *(const uint4*)(xq_ + ar * 128 + ((c16_ ^ ar7) << 4)); \
        B8 wf_; wf_.u = *(const uint4*)(wq_ + an * 128 + ((c16_ ^ an7) << 4)); \
        acc = __builtin_amdgcn_mfma_f32_32x32x16_bf16(af_.v, wf_.v, acc, 0, 0, 0); } }

  f32x16 acc = {};   // 32 rows x 32 cols for this wave

  // prologue: stage chunk 0
  LOADX(0) LOADW(0)
  WRITEX(xsm[0]) WRITEW(wsm[0])                    // compiler waits vmcnt
  asm volatile("s_waitcnt lgkmcnt(0)" ::: "memory");
  __builtin_amdgcn_s_barrier();                    // chunk 0 staged (all waves)
  asm volatile("" ::: "memory");

  for (int c = 0; c < 16; ++c) {
    if (c < 15) { LOADX(c + 1) LOADW(c + 1) }      // issue next chunk -> regs
    COMPUTE(xsm[c & 1], wsm[c & 1])                // MFMA chunk c from LDS
    if (c < 15) {
      WRITEX(xsm[(c + 1) & 1]) WRITEW(wsm[(c + 1) & 1])
      asm volatile("s_waitcnt lgkmcnt(0)" ::: "memory");
      __builtin_amdgcn_s_barrier();                // next buf ready; cur free
      asm volatile("" ::: "memory");
    }
  }

  #undef LOADX
  #undef LOADW
  #undef WX1
  #undef WRITEX
  #undef WRITEW
  #undef COMPUTE

  // epilogue: bias add, un-swizzled [64 m][64 n] bf16 tile (disjoint per wave)
  #pragma unroll
  for (int r = 0; r < 16; ++r) {
    int mrow = (r & 3) + 8 * (r >> 2) + 4 * half;   // C row map (m74/m101)
    cs[((wr << 5) + mrow) * 64 + an] = (bf16)(acc[r] + b0v);
  }
  __syncthreads();

  if (mat < 2) {
    // q/k: row-major [16384][64] bf16, chunk c of row s at slot c^(s&7)
    bf16* gout = (mat == 0) ? qo : ko;
    #pragma unroll
    for (int p = 0; p < 2; ++p) {
      int id = p * 256 + tid;     // 0..511
      int r = id >> 3;            // 0..63
      int c = id & 7;
      *(uint4*)(gout + (size_t)(m0 + r) * 64 + (c ^ (r & 7)) * 8) =
          *(const uint4*)(cs + r * 64 + c * 8);   // m0 % 64 == 0 -> (m0+r)&7 == r&7
    }
  } else {
    // v: transposed [b][64 d][4096 s] bf16; strip == one full 64-key tile
    int batch = m0 >> 12;
    int tb = m0 & 4095;           // 64-key tile base (64-aligned)
    #pragma unroll
    for (int p = 0; p < 2; ++p) {
      int id = p * 256 + tid;     // 0..511
      int d = id >> 3;            // 0..63
      int j = id & 7;             // logical chunk in the 64-key tile
      union { bf16 b[8]; uint4 u; } pk;
      #pragma unroll
      for (int t = 0; t < 8; ++t) pk.b[t] = cs[(j * 8 + t) * 64 + d];
      *(uint4*)(vTo + ((size_t)batch * 64 + d) * 4096 + tb + (j ^ (d & 7)) * 8) = pk.u;
    }
  }
}

// ---------------------------------------------------------------------------
// flash: block = 64 queries (one batch), 4 waves, wave w owns keys
//        [w*1024, w*1024+1024) in 16 tiles of 64; wave-private LDS streams.
// ---------------------------------------------------------------------------
__global__ __launch_bounds__(256, 2) void flash_kernel(
    const bf16* __restrict__ qb, const bf16* __restrict__ kb, const bf16* __restrict__ vT,
    const float* __restrict__ biasArr, float* __restrict__ out)
{
  __shared__ __align__(16) char smem[65536];
  bf16* ksb = (bf16*)smem;            // [4][64*64] K tiles
  bf16* vsb = (bf16*)(smem + 32768);  // [4][64*64] V^T tiles

  const int tid = threadIdx.x;
  const int lane = tid & 63;
  const int wv = tid >> 6;
  const int half = lane >> 5;
  const int ln = lane & 31;

  const int batch = blockIdx.x >> 6;
  const int q0 = (blockIdx.x & 63) << 6;

  // Q fragments for both 32-query blocks (stay in registers)
  bf16x8 qf[2][4];
  const bf16* qbase = qb + ((size_t)batch * 4096 + q0) * 64;
  #pragma unroll
  for (int qk = 0; qk < 2; ++qk)
  #pragma unroll
  for (int s = 0; s < 4; ++s) {
    int qq = (qk << 5) + ln;
    int phys = (2 * s + half) ^ (qq & 7);
    B8 t; t.u = *(const uint4*)(qbase + qq * 64 + phys * 8);
    qf[qk][s] = t.v;
  }

  f32x16 acc[2][2] = {{{}, {}}, {{}, {}}};   // [qblk][d-half], C: col=q, rows=d
  float den0 = 0.f, den1 = 0.f;

  bf16* kds = ksb + wv * 4096;
  bf16* vds = vsb + wv * 4096;
  const bf16* kgb = kb + (size_t)batch * 4096 * 64;
  const bf16* vgb = vT + (size_t)batch * 64 * 4096;
  const float* barr = biasArr + batch * 4096;

  for (int it = 0; it < 16; ++it) {
    const int key0 = wv * 1024 + it * 64;
    __syncthreads();  // drain previous tile's ds_reads before DMA overwrites
    // stage K tile [64 keys][64 d] (8KB contiguous in global)
    const bf16* ksrc = kgb + (size_t)key0 * 64;
    #pragma unroll
    for (int i = 0; i < 8; ++i)
      async16((const char*)ksrc + i * 1024 + lane * 16, (char*)kds + i * 1024);
    // stage V^T tile [64 d][64 keys] (128B per d-row, stride 8KB)
    const bf16* vsrc = vgb + key0;
    #pragma unroll
    for (int i = 0; i < 8; ++i)
      async16((const char*)vsrc + ((size_t)(i * 8 + (lane >> 3)) * 4096 + (lane & 7) * 8) * 2,
              (char*)vds + i * 1024);
    __syncthreads();  // DMA complete

    #pragma unroll
    for (int st = 0; st < 2; ++st) {
      // S^T tile = K * Q^T : rows = 32 keys, cols = 32 queries
      f32x16 s0 = {};
      f32x16 s1 = {};
      #pragma unroll
      for (int s = 0; s < 4; ++s) {
        int key = (st << 5) + ln;
        B8 af; af.u = *(const uint4*)(kds + key * 64 + (((2 * s + half) ^ (key & 7)) << 3));
        s0 = __builtin_amdgcn_mfma_f32_32x32x16_bf16(af.v, qf[0][s], s0, 0, 0, 0);
        s1 = __builtin_amdgcn_mfma_f32_32x32x16_bf16(af.v, qf[1][s], s1, 0, 0, 0);
      }
      // bias per C-row (key): reg r -> key (r&3)+8*(r>>2)+4*half (tile-local)
      float bb[16];
      #pragma unroll
      for (int g = 0; g < 4; ++g)
        *(float4*)&bb[4 * g] = *(const float4*)(barr + key0 + (st << 5) + 8 * g + (half << 2));
      // p = exp2(s*KSC + bias); accumulate denominator; pack bf16 pairs
      uint32_t pk0[8], pk1[8];
      #pragma unroll
      for (int i = 0; i < 8; ++i) {
        float a0 = __builtin_amdgcn_exp2f(fmaf(s0[2 * i],     KSC, bb[2 * i]));
        float a1 = __builtin_amdgcn_exp2f(fmaf(s0[2 * i + 1], KSC, bb[2 * i + 1]));
        float c0 = __builtin_amdgcn_exp2f(fmaf(s1[2 * i],     KSC, bb[2 * i]));
        float c1 = __builtin_amdgcn_exp2f(fmaf(s1[2 * i + 1], KSC, bb[2 * i + 1]));
        den0 += a0 + a1;
        den1 += c0 + c1;
        union { bf16 b[2]; uint32_t u; } u0, u1;
        u0.b[0] = (bf16)a0; u0.b[1] = (bf16)a1;
        u1.b[0] = (bf16)c0; u1.b[1] = (bf16)c1;
        pk0[i] = u0.u; pk1[i] = u1.u;
      }
      // lane-pair exchange: C-layout P^T -> B-operand fragments
      uint32_t xp0[8], xp1[8];
      #pragma unroll
      for (int i = 0; i < 8; ++i) {
        xp0[i] = (uint32_t)__shfl_xor((int)pk0[i], 32);
        xp1[i] = (uint32_t)__shfl_xor((int)pk1[i], 32);
      }
      #pragma unroll
      for (int t = 0; t < 2; ++t) {
        B8 p0f, p1f;
        p0f.w[0] = half ? xp0[4 * t + 2] : pk0[4 * t];
        p0f.w[1] = half ? xp0[4 * t + 3] : pk0[4 * t + 1];
        p0f.w[2] = half ? pk0[4 * t + 2] : xp0[4 * t];
        p0f.w[3] = half ? pk0[4 * t + 3] : xp0[4 * t + 1];
        p1f.w[0] = half ? xp1[4 * t + 2] : pk1[4 * t];
        p1f.w[1] = half ? xp1[4 * t + 3] : pk1[4 * t + 1];
        p1f.w[2] = half ? pk1[4 * t + 2] : xp1[4 * t];
        p1f.w[3] = half ? pk1[4 * t + 3] : xp1[4 * t + 1];
        #pragma unroll
        for (int dh = 0; dh < 2; ++dh) {
          int d = (dh << 5) + ln;
          B8 vf; vf.u = *(const uint4*)(vds + d * 64 +
                          ((((st << 2) + (t << 1) + half) ^ (d & 7)) << 3));
          acc[0][dh] = __builtin_amdgcn_mfma_f32_32x32x16_bf16(vf.v, p0f.v, acc[0][dh], 0, 0, 0);
          acc[1][dh] = __builtin_amdgcn_mfma_f32_32x32x16_bf16(vf.v, p1f.v, acc[1][dh], 0, 0, 0);
        }
      }
    }
  }

  // full denominator per query (each half-lane saw half the keys)
  den0 += __shfl_xor(den0, 32);
  den1 += __shfl_xor(den1, 32);

  // pairwise combine of the 4 key-split partials through LDS (<= 35KB overlay)
  float* nb = (float*)smem;              // [2][64*68]
  float* dn = (float*)(smem + 34816);    // [2][64]

  __syncthreads();
  if (wv >= 2) {
    float* mynb = nb + (wv - 2) * 4352;
    #pragma unroll
    for (int qk = 0; qk < 2; ++qk)
    #pragma unroll
    for (int dh = 0; dh < 2; ++dh)
    #pragma unroll
    for (int g = 0; g < 4; ++g) {
      int q = (qk << 5) + ln;
      int d = 8 * g + (half << 2) + (dh << 5);
      f32x16 a = acc[qk][dh];
      *(float4*)(mynb + q * 68 + d) = make_float4(a[4*g], a[4*g+1], a[4*g+2], a[4*g+3]);
    }
    if (half == 0) {
      dn[(wv - 2) * 64 + ln]      = den0;
      dn[(wv - 2) * 64 + 32 + ln] = den1;
    }
  }
  __syncthreads();
  if (wv < 2) {
    float* pb = nb + wv * 4352;
    #pragma unroll
    for (int qk = 0; qk < 2; ++qk)
    #pragma unroll
    for (int dh = 0; dh < 2; ++dh)
    #pragma unroll
    for (int g = 0; g < 4; ++g) {
      int q = (qk << 5) + ln;
      int d = 8 * g + (half << 2) + (dh << 5);
      float4 t = *(const float4*)(pb + q * 68 + d);
      acc[qk][dh][4*g+0] += t.x; acc[qk][dh][4*g+1] += t.y;
      acc[qk][dh][4*g+2] += t.z; acc[qk][dh][4*g+3] += t.w;
    }
    den0 += dn[wv * 64 + ln];
    den1 += dn[wv * 64 + 32 + ln];
  }
  __syncthreads();
  if (wv < 2) {
    float* mynb = nb + wv * 4352;
    #pragma unroll
    for (int qk = 0; qk < 2; ++qk)
    #pragma unroll
    for (int dh = 0; dh < 2; ++dh)
    #pragma unroll
    for (int g = 0; g < 4; ++g) {
      int q = (qk << 5) + ln;
      int d = 8 * g + (half << 2) + (dh << 5);
      f32x16 a = acc[qk][dh];
      *(float4*)(mynb + q * 68 + d) = make_float4(a[4*g], a[4*g+1], a[4*g+2], a[4*g+3]);
    }
    if (half == 0) {
      dn[wv * 64 + ln]      = den0;
      dn[wv * 64 + 32 + ln] = den1;
    }
  }
  __syncthreads();
  // final: out[q][d] = (nb0+nb1)/(dn0+dn1), coalesced float4 stores
  #pragma unroll
  for (int p = 0; p < 4; ++p) {
    int i = p * 256 + tid;
    int qq = i >> 4;
    int d4 = (i & 15) << 2;
    float4 A = *(const float4*)(nb + qq * 68 + d4);
    float4 Bv = *(const float4*)(nb + 4352 + qq * 68 + d4);
    float dd = dn[qq] + dn[64 + qq];
    float inv = 1.0f / dd;
    float4 o = make_float4((A.x + Bv.x) * inv, (A.y + Bv.y) * inv,
                           (A.z + Bv.z) * inv, (A.w + Bv.w) * inv);
    *(float4*)(out + ((size_t)batch * 4096 + q0 + qq) * 64 + d4) = o;
  }
}

// ---------------------------------------------------------------------------
extern "C" void kernel_launch(void* const* d_in, const int* in_sizes, int n_in,
                              void* d_out, int out_size, void* d_ws, size_t ws_size,
                              hipStream_t stream)
{
  const float* query = (const float*)d_in[0];
  const float* key   = (const float*)d_in[1];
  const float* value = (const float*)d_in[2];
  const int*   mask  = (const int*)d_in[3];
  const float* Wq    = (const float*)d_in[4];
  const float* bq    = (const float*)d_in[5];
  const float* Wk    = (const float*)d_in[6];
  const float* bk    = (const float*)d_in[7];
  const float* Wv    = (const float*)d_in[8];
  const float* bv    = (const float*)d_in[9];
  float* out = (float*)d_out;

  // workspace carve (bf16 elems): q 1M, k 1M, vT 1M, wT 192K, bias 16K floats
  bf16* qb = (bf16*)d_ws;
  bf16* kb = qb + 1048576;
  bf16* vT = kb + 1048576;
  bf16* wT = vT + 1048576;                       // 3*64*1024
  float* biasArr = (float*)((char*)d_ws + 3 * 2097152 + 393216);

  setup_kernel<<<112, 256, 0, stream>>>(Wq, Wk, Wv, mask, wT, biasArr);
  proj_kernel<<<768, 256, 0, stream>>>(query, key, value, wT, bq, bk, bv, qb, kb, vT);
  flash_kernel<<<256, 256, 0, stream>>>(qb, kb, vT, biasArr, out);
}